// Round 1
// baseline (1446.176 us; speedup 1.0000x reference)
//
#include <hip/hip_runtime.h>
#include <hip/hip_bf16.h>
#include <math.h>

#define NNODES 4096
#define ALPHA  0.2f

// ---------------------------------------------------------------------------
// Generic tiled GEMM: C[i][c] = sum_f A[i*lda+f] * W[(c>>6)*K*64 + f*64 + (c&63)]
// W is head-blocked [H][K][64]; for H=1 (layer 2) this is plain row-major [K][64].
// Block: 256 threads, 64x64 output tile, K-step 16.
// ---------------------------------------------------------------------------
__global__ __launch_bounds__(256) void gemm_xw(
    const float* __restrict__ A, int lda,
    const float* __restrict__ Wp, int K,
    float* __restrict__ C, int ldc)
{
    __shared__ float As[64][17];  // [i][k], pad 17
    __shared__ float Bs[16][68];  // [k][c], pad 68 (16B-aligned float4 reads)
    const int i0 = blockIdx.x * 64;
    const int c0 = blockIdx.y * 64;
    const int t  = threadIdx.x;
    const int tx = t & 15, ty = t >> 4;
    const float* Wbase = Wp + (size_t)(c0 >> 6) * K * 64;  // head base
    float acc[4][4] = {};
    for (int k0 = 0; k0 < K; k0 += 16) {
        #pragma unroll
        for (int rep = 0; rep < 4; rep++) {
            int idx = rep * 256 + t;
            int ii = idx >> 4, kk = idx & 15;
            As[ii][kk] = A[(size_t)(i0 + ii) * lda + k0 + kk];
        }
        #pragma unroll
        for (int rep = 0; rep < 4; rep++) {
            int idx = rep * 256 + t;
            int kk = idx >> 6, cc = idx & 63;
            Bs[kk][cc] = Wbase[(size_t)(k0 + kk) * 64 + cc];
        }
        __syncthreads();
        #pragma unroll
        for (int kk = 0; kk < 16; kk++) {
            float a[4];
            #pragma unroll
            for (int r = 0; r < 4; r++) a[r] = As[ty * 4 + r][kk];
            float4 b4 = *(const float4*)&Bs[kk][tx * 4];
            float b[4] = {b4.x, b4.y, b4.z, b4.w};
            #pragma unroll
            for (int r = 0; r < 4; r++)
                #pragma unroll
                for (int c = 0; c < 4; c++) acc[r][c] += a[r] * b[c];
        }
        __syncthreads();
    }
    #pragma unroll
    for (int r = 0; r < 4; r++)
        #pragma unroll
        for (int c = 0; c < 4; c++)
            C[(size_t)(i0 + ty * 4 + r) * ldc + c0 + tx * 4 + c] = acc[r][c];
}

// ---------------------------------------------------------------------------
// f_src[h][n] = Wh[n, h*64:+64] . a[h][0:64] ; f_dst uses a[h][64:128]
// ---------------------------------------------------------------------------
__global__ void feat_fdot(const float* __restrict__ Wh, int ldw, int H, int Nn,
                          const float* __restrict__ a,
                          float* __restrict__ fs, float* __restrict__ fd)
{
    int id = blockIdx.x * blockDim.x + threadIdx.x;
    if (id >= H * Nn) return;
    int h = id / Nn, n = id % Nn;
    const float* row = Wh + (size_t)n * ldw + h * 64;
    const float* as  = a + h * 128;
    const float* ad  = as + 64;
    float s = 0.f, d = 0.f;
    #pragma unroll 8
    for (int k = 0; k < 64; k++) { float v = row[k]; s += v * as[k]; d += v * ad[k]; }
    fs[id] = s; fd[id] = d;
}

// M[h] = max_n fd[h][n]
__global__ void rowmax_k(const float* __restrict__ fd, int Nn, float* __restrict__ M)
{
    __shared__ float red[256];
    int h = blockIdx.x;
    float m = -INFINITY;
    for (int n = threadIdx.x; n < Nn; n += 256) m = fmaxf(m, fd[(size_t)h * Nn + n]);
    red[threadIdx.x] = m;
    __syncthreads();
    for (int s = 128; s > 0; s >>= 1) {
        if (threadIdx.x < (unsigned)s) red[threadIdx.x] = fmaxf(red[threadIdx.x], red[threadIdx.x + s]);
        __syncthreads();
    }
    if (threadIdx.x == 0) M[h] = red[0];
}

// ---------------------------------------------------------------------------
// Fused masked-softmax attention + P@Wh + ELU.
// Block: 256 threads = 64-row tile x 64 dims, one head (blockIdx.y).
// J-loop in tiles of 32. Global-max bound c[i]=leaky(fs[i]+max_j fd[j]) makes
// this single-pass (no online rescale). Denominator via half-wave reduce.
// ---------------------------------------------------------------------------
__global__ __launch_bounds__(256) void gat_attn(
    const float* __restrict__ adj,
    const float* __restrict__ Whb, int ldb,   // B operand: Whb[j*ldb + hoff + d]
    const float* __restrict__ fs, const float* __restrict__ fd,
    const float* __restrict__ Mh,
    int Nn,
    float* __restrict__ out, int ldo)
{
    __shared__ float Pt[32][68];   // [j][i]  (transposed P tile), pad 68
    __shared__ float Wt[32][68];   // [j][d]
    __shared__ float fsl[64], cl[64], denom[64], fdl[32];
    const int i0   = blockIdx.x * 64;
    const int h    = blockIdx.y;
    const int hoff = h * 64;
    const int t    = threadIdx.x;
    const int tx   = t & 15, ty = t >> 4;
    const float M  = Mh[h];
    if (t < 64) {
        float f = fs[(size_t)h * Nn + i0 + t];
        fsl[t] = f;
        float e = f + M;
        cl[t] = e >= 0.f ? e : ALPHA * e;
        denom[t] = 0.f;
    }
    float acc[4][4] = {};
    __syncthreads();

    for (int j0 = 0; j0 < Nn; j0 += 32) {
        if (t < 32) fdl[t] = fd[(size_t)h * Nn + j0 + t];
        __syncthreads();
        // --- score phase: P[i][j] for 64x32 tile, 8 entries/thread ---
        #pragma unroll
        for (int rep = 0; rep < 8; rep++) {
            int i = rep * 8 + (t >> 5);
            int j = t & 31;
            float av = adj[(size_t)(i0 + i) * Nn + j0 + j];
            float e = fsl[i] + fdl[j];
            e = e >= 0.f ? e : ALPHA * e;
            float p = (av > 0.f) ? __expf(e - cl[i]) : 0.f;
            Pt[j][i] = p;
            float s = p;
            s += __shfl_xor(s, 1);  s += __shfl_xor(s, 2);  s += __shfl_xor(s, 4);
            s += __shfl_xor(s, 8);  s += __shfl_xor(s, 16);
            if ((t & 31) == 0) denom[i] += s;   // unique i per (rep, half-wave)
        }
        // --- load Wh tile 32x64 ---
        #pragma unroll
        for (int rep = 0; rep < 8; rep++) {
            int idx = rep * 256 + t;
            int jj = idx >> 6, dd = idx & 63;
            Wt[jj][dd] = Whb[(size_t)(j0 + jj) * ldb + hoff + dd];
        }
        __syncthreads();
        // --- FMA phase: acc += P^T-tile x Wh-tile ---
        #pragma unroll
        for (int kk = 0; kk < 32; kk++) {
            float4 a4 = *(const float4*)&Pt[kk][ty * 4];
            float4 b4 = *(const float4*)&Wt[kk][tx * 4];
            float a[4] = {a4.x, a4.y, a4.z, a4.w};
            float b[4] = {b4.x, b4.y, b4.z, b4.w};
            #pragma unroll
            for (int r = 0; r < 4; r++)
                #pragma unroll
                for (int c = 0; c < 4; c++) acc[r][c] += a[r] * b[c];
        }
        __syncthreads();
    }

    // --- epilogue: divide by denom, ELU, store ---
    #pragma unroll
    for (int r = 0; r < 4; r++) {
        int i = ty * 4 + r;
        float dn = denom[i];
        dn = dn > 0.f ? dn : 1.f;
        float inv = 1.f / dn;
        #pragma unroll
        for (int c = 0; c < 4; c++) {
            float v = acc[r][c] * inv;
            v = v > 0.f ? v : expm1f(v);
            out[(size_t)(i0 + i) * ldo + hoff + tx * 4 + c] = v;
        }
    }
}

// ---------------------------------------------------------------------------
extern "C" void kernel_launch(void* const* d_in, const int* in_sizes, int n_in,
                              void* d_out, int out_size, void* d_ws, size_t ws_size,
                              hipStream_t stream)
{
    (void)in_sizes; (void)n_in; (void)out_size; (void)ws_size;
    const float* x   = (const float*)d_in[0];   // [4096,512]
    const float* adj = (const float*)d_in[1];   // [4096,4096]
    const float* W   = (const float*)d_in[2];   // [8,512,64]
    const float* a   = (const float*)d_in[3];   // [8,128]
    const float* Wo  = (const float*)d_in[4];   // [512,64]
    const float* ao  = (const float*)d_in[5];   // [128]
    float* outp = (float*)d_out;                // [4096,64]

    char* ws = (char*)d_ws;
    float* whc = (float*)(ws);                       // [4096,512] layer-1 Wh (concat layout)
    float* h1  = (float*)(ws + (8u << 20));          // [4096,512] layer-1 output
    float* fs1 = (float*)(ws + (16u << 20));         // [8,4096]
    float* fd1 = (float*)(ws + (16u << 20) + 131072);
    float* M1  = (float*)(ws + (16u << 20) + 262144);
    float* fs2 = (float*)(ws + (16u << 20) + 266240);
    float* fd2 = (float*)(ws + (16u << 20) + 282624);
    float* M2  = (float*)(ws + (16u << 20) + 299008);
    float* wh2 = whc;                                // reuse: whc dead after layer-1 attn

    dim3 b256(256);
    // ---- layer 1 ----
    gemm_xw<<<dim3(64, 8), b256, 0, stream>>>(x, 512, W, 512, whc, 512);
    feat_fdot<<<dim3(8 * NNODES / 256), b256, 0, stream>>>(whc, 512, 8, NNODES, a, fs1, fd1);
    rowmax_k<<<dim3(8), b256, 0, stream>>>(fd1, NNODES, M1);
    gat_attn<<<dim3(NNODES / 64, 8), b256, 0, stream>>>(adj, whc, 512, fs1, fd1, M1, NNODES, h1, 512);
    // ---- layer 2 ----
    gemm_xw<<<dim3(64, 1), b256, 0, stream>>>(h1, 512, Wo, 512, wh2, 64);
    feat_fdot<<<dim3(NNODES / 256), b256, 0, stream>>>(wh2, 64, 1, NNODES, ao, fs2, fd2);
    rowmax_k<<<dim3(1), b256, 0, stream>>>(fd2, NNODES, M2);
    gat_attn<<<dim3(NNODES / 64, 1), b256, 0, stream>>>(adj, wh2, 64, fs2, fd2, M2, NNODES, outp, 64);
}